// Round 12
// baseline (990.995 us; speedup 1.0000x reference)
//
#include <hip/hip_runtime.h>
#include <cstdint>
#include <cstddef>

// ---------------------------------------------------------------------------
// VirtualNodeGNN: 3x GENConv(softmax aggr) + virtual node + mean pool.
// R12 changes vs R11 (827 us):
//   - GEMM1 rewritten barrier-free: W1T (256KB) is L2-resident -> B loaded
//     global->reg directly (no ldsB, no k-loop barriers). A[128x256] staged
//     once in 64KB LDS. R11 was LDS-issue bound: 18 ds_read_b128 (~216cyc)
//     per 16 MFMAs (~77cyc) + 2 barriers per 64-k step.
//   - vnsum + next-layer LN fused into k_vnln (block-per-batch; vn[b] is
//     block-local since batch rows are contiguous); final vnsum + lnpool
//     fused into k_vnlnpool. -4 dispatches, -~150MB h re-reads.
//   - note: SQ_LDS_BANK_CONFLICT on b128 staging is inherent serialization
//     (1024B/op vs 128B/cyc LDS), ~1us total -- not actionable.
// ---------------------------------------------------------------------------

typedef _Float16 half8_t __attribute__((ext_vector_type(8)));
typedef _Float16 half4_t __attribute__((ext_vector_type(4)));
typedef float    floatx4 __attribute__((ext_vector_type(4)));

#define DEVINL __device__ __forceinline__

DEVINL float wave_sum(float v) {
#pragma unroll
  for (int m = 32; m; m >>= 1) v += __shfl_xor(v, m, 64);
  return v;
}

// ------------------------------- node encoder ------------------------------
__global__ __launch_bounds__(256) void k_node_enc(
    const float* __restrict__ x, const float* __restrict__ W,
    const float* __restrict__ bias, _Float16* __restrict__ h, int Nr) {
  __shared__ float sW[9 * 256];
  __shared__ float sb[256];
  __shared__ float sx[72];
  const int j = threadIdx.x;
#pragma unroll
  for (int k = 0; k < 9; ++k) sW[k * 256 + j] = W[k * 256 + j];
  sb[j] = bias[j];
  const int row0 = blockIdx.x * 8;
  if (j < 72) {
    int p = row0 * 9 + j;
    sx[j] = (p < Nr * 9) ? x[p] : 0.f;
  }
  __syncthreads();
  for (int r = 0; r < 8; ++r) {
    int row = row0 + r;
    if (row >= Nr) break;
    float acc = sb[j];
#pragma unroll
    for (int k = 0; k < 9; ++k) acc = fmaf(sx[r * 9 + k], sW[k * 256 + j], acc);
    h[(size_t)row * 256 + j] = (_Float16)acc;
  }
}

// ---------------- batch ptr via binary search (batch sorted) ---------------
__global__ void k_bptr(const int* __restrict__ batch, int* __restrict__ bptr,
                       int N_, int B_) {
  int b = blockIdx.x * 256 + threadIdx.x;
  if (b > B_) return;
  int lo = 0, hi = N_;
  while (lo < hi) {
    int mid = (lo + hi) >> 1;
    if (batch[mid] < b) lo = mid + 1; else hi = mid;
  }
  bptr[b] = lo;
}

// ------------------------- CSR build (dst-sorted) --------------------------
__global__ void k_deg(const int* __restrict__ ei, int* __restrict__ deg, int E_) {
  int e = blockIdx.x * 256 + threadIdx.x;
  if (e < E_) atomicAdd(&deg[ei[E_ + e]], 1);  // row 1 of edge_index = dst
}

__global__ __launch_bounds__(256) void k_scan1(
    const int* __restrict__ in, int* __restrict__ out1, int* __restrict__ bsum, int n) {
  __shared__ int tmp[256];
  const int t = threadIdx.x;
  const int base = blockIdx.x * 1024;
  int v[4];
  int run = 0;
#pragma unroll
  for (int i = 0; i < 4; ++i) {
    int p = base + t * 4 + i;
    int xv = (p < n) ? in[p] : 0;
    run += xv;
    v[i] = run;
  }
  tmp[t] = run;
  __syncthreads();
  for (int off = 1; off < 256; off <<= 1) {
    int u = (t >= off) ? tmp[t - off] : 0;
    __syncthreads();
    tmp[t] += u;
    __syncthreads();
  }
  int excl = tmp[t] - run;
#pragma unroll
  for (int i = 0; i < 4; ++i) {
    int p = base + t * 4 + i;
    if (p < n) out1[p] = v[i] + excl;
  }
  if (t == 255) bsum[blockIdx.x] = tmp[255];
}

__global__ void k_scan2(int* bsum, int nb, int* ptr0) {
  if (threadIdx.x == 0 && blockIdx.x == 0) {
    int run = 0;
    for (int i = 0; i < nb; ++i) { int xv = bsum[i]; bsum[i] = run; run += xv; }
    ptr0[0] = 0;
  }
}

__global__ __launch_bounds__(256) void k_scan3(int* out1, const int* __restrict__ bsum, int n) {
  int add = bsum[blockIdx.x];
  int p0 = blockIdx.x * 1024 + threadIdx.x * 4;
#pragma unroll
  for (int i = 0; i < 4; ++i) {
    int p = p0 + i;
    if (p < n) out1[p] += add;
  }
}

__global__ void k_copy(const int* __restrict__ a, int* __restrict__ b, int n) {
  int i = blockIdx.x * 256 + threadIdx.x;
  if (i < n) b[i] = a[i];
}

__global__ void k_csrfill(const int* __restrict__ ei, int* __restrict__ cursor,
                          int* __restrict__ csr_src, int* __restrict__ csr_eid, int E_) {
  int e = blockIdx.x * 256 + threadIdx.x;
  if (e < E_) {
    int d = ei[E_ + e];
    int pos = atomicAdd(&cursor[d], 1);
    csr_src[pos] = ei[e];
    csr_eid[pos] = e;
  }
}

__global__ void k_vninit(const float* __restrict__ emb, float* __restrict__ vn) {
  vn[(size_t)blockIdx.x * 256 + threadIdx.x] = emb[threadIdx.x];
}

// ----------------- all-weights transpose+convert (one launch) --------------
__global__ __launch_bounds__(256) void k_wcvt_all(
    const float* __restrict__ W1, const float* __restrict__ W2,
    _Float16* __restrict__ W1T, _Float16* __restrict__ W2T) {
  int idx = blockIdx.x * 256 + threadIdx.x;
  int mat = idx >> 17;
  int rem = idx & 131071;
  if (mat < 3) {
    int k = rem >> 9, n = rem & 511;
    W1T[(size_t)mat * 131072 + (size_t)n * 256 + k] =
        (_Float16)W1[(size_t)mat * 131072 + rem];
  } else {
    int m = mat - 3;
    int k = rem >> 8, n = rem & 255;
    W2T[(size_t)m * 131072 + (size_t)n * 512 + k] =
        (_Float16)W2[(size_t)m * 131072 + rem];
  }
}

// ------------------------------ LayerNorm 256 ------------------------------
// used once (layer 1, no vn pending)
__global__ __launch_bounds__(256) void k_ln256(
    const _Float16* __restrict__ h, const float* __restrict__ g,
    const float* __restrict__ b, _Float16* __restrict__ out, int Nr) {
  int row = blockIdx.x * 4 + (threadIdx.x >> 6);
  if (row >= Nr) return;
  int lane = threadIdx.x & 63;
  half4_t xh = *(const half4_t*)(h + (size_t)row * 256 + lane * 4);
  float x0 = (float)xh[0], x1 = (float)xh[1], x2 = (float)xh[2], x3 = (float)xh[3];
  float s = wave_sum(x0 + x1 + x2 + x3);
  float mu = s * (1.f / 256.f);
  float d0 = x0 - mu, d1 = x1 - mu, d2 = x2 - mu, d3 = x3 - mu;
  float v = wave_sum(d0 * d0 + d1 * d1 + d2 * d2 + d3 * d3);
  float rstd = rsqrtf(v * (1.f / 256.f) + 1e-5f);
  float4 gv = *(const float4*)(g + lane * 4);
  float4 bv = *(const float4*)(b + lane * 4);
  half4_t o;
  o[0] = (_Float16)fmaxf(d0 * rstd * gv.x + bv.x, 0.f);
  o[1] = (_Float16)fmaxf(d1 * rstd * gv.y + bv.y, 0.f);
  o[2] = (_Float16)fmaxf(d2 * rstd * gv.z + bv.z, 0.f);
  o[3] = (_Float16)fmaxf(d3 * rstd * gv.w + bv.w, 0.f);
  *(half4_t*)(out + (size_t)row * 256 + lane * 4) = o;
}

// --------------------------- softmax aggregation ---------------------------
__global__ __launch_bounds__(256) void k_aggregate(
    const _Float16* __restrict__ hn, const float* __restrict__ eattr,
    const float* __restrict__ edgeW, const float* __restrict__ edgeB,
    const int* __restrict__ indptr, const int* __restrict__ csr_src,
    const int* __restrict__ csr_eid, const float* __restrict__ tptr,
    _Float16* __restrict__ agg, int Nr) {
  int node = blockIdx.x * 4 + (threadIdx.x >> 6);
  if (node >= Nr) return;
  int lane = threadIdx.x & 63;
  int j0 = lane * 4;
  float4 w0 = *(const float4*)(edgeW + j0);
  float4 w1 = *(const float4*)(edgeW + 256 + j0);
  float4 w2 = *(const float4*)(edgeW + 512 + j0);
  float4 wb = *(const float4*)(edgeB + j0);
  float W0[4] = {w0.x, w0.y, w0.z, w0.w};
  float W1r[4] = {w1.x, w1.y, w1.z, w1.w};
  float W2r[4] = {w2.x, w2.y, w2.z, w2.w};
  float WB[4] = {wb.x, wb.y, wb.z, wb.w};
  float tval = tptr[0];
  int e0 = indptr[node], e1 = indptr[node + 1];
  float D[4] = {0.f, 0.f, 0.f, 0.f};
  float Nu[4] = {0.f, 0.f, 0.f, 0.f};
  for (int s = e0; s < e1; ++s) {
    int srcn = csr_src[s];
    int eid = csr_eid[s];
    float ex0 = eattr[(size_t)eid * 3 + 0];
    float ex1 = eattr[(size_t)eid * 3 + 1];
    float ex2 = eattr[(size_t)eid * 3 + 2];
    half4_t hv = *(const half4_t*)(hn + (size_t)srcn * 256 + j0);
#pragma unroll
    for (int i = 0; i < 4; ++i) {
      float eaj = fmaf(ex0, W0[i], fmaf(ex1, W1r[i], fmaf(ex2, W2r[i], WB[i])));
      float msg = fmaxf((float)hv[i] + eaj, 0.f) + 1e-7f;
      float pr = __expf(msg * tval);
      D[i] += pr;
      Nu[i] = fmaf(pr, msg, Nu[i]);
    }
  }
  half4_t hs = *(const half4_t*)(hn + (size_t)node * 256 + j0);
  half4_t res;
#pragma unroll
  for (int i = 0; i < 4; ++i)
    res[i] = (_Float16)(Nu[i] / (D[i] + 1e-16f) + (float)hs[i]);
  *(half4_t*)(agg + (size_t)node * 256 + j0) = res;
}

// ------------------------------- GEMM1 -------------------------------------
// t1[M,512] = agg[M,256] @ W1 + b1 (f16 out) + rstat[row] = (sum, sum^2).
// Block = 128 rows x ALL 512 cols. A[128x256] staged ONCE (64KB LDS,
// XOR-swizzled); B (W1T, 256KB, L2-resident) loaded global->register with
// depth-1 prefetch -- NO ldsB, NO barriers in the k-loop. Wave owns
// 32 rows x 128 cols per n-tile; row sums in regs, rstat direct store.
__global__ __launch_bounds__(256, 2) void k_gemm1(
    const _Float16* __restrict__ A, const _Float16* __restrict__ BT,
    const float* __restrict__ bias, _Float16* __restrict__ outh,
    float2* __restrict__ rstat, int M) {
  __shared__ _Float16 ldsA[128 * 256];   // 64 KB
  const int tid = threadIdx.x;
  const int lane = tid & 63;
  const int wv = tid >> 6;
  const int m0 = blockIdx.x * 128;
  const int wm = wv * 32;                // wave owns rows [wm, wm+32)
  const int q = lane >> 4;
  const int l16 = lane & 15;

  // ---- stage A once: 4096 16B chunks; slot s holds logical (r, c^(r&7)) ----
  for (int g = 0; g < 4; ++g) {
    half8_t tmp[4];
    int ss[4];
#pragma unroll
    for (int i = 0; i < 4; ++i) {
      int s = (g * 4 + i) * 256 + tid;
      int r = s >> 5;
      int c = (s & 31) ^ (r & 7);
      int rowA = m0 + r;
      rowA = rowA < M ? rowA : (M - 1);
      tmp[i] = *(const half8_t*)(A + (size_t)rowA * 256 + c * 8);
      ss[i] = s;
    }
#pragma unroll
    for (int i = 0; i < 4; ++i)
      *(half8_t*)(ldsA + (size_t)ss[i] * 8) = tmp[i];
  }
  __syncthreads();  // the ONLY barrier

  float sA[2][4] = {};
  float s2A[2][4] = {};

  for (int n = 0; n < 4; ++n) {
    const _Float16* Bn = BT + (size_t)(n * 128 + l16) * 256 + q * 8;
    floatx4 acc[2][8] = {};
    half8_t bfn[8];
#pragma unroll
    for (int ct = 0; ct < 8; ++ct)
      bfn[ct] = *(const half8_t*)(Bn + ct * 4096);
#pragma unroll
    for (int kk = 0; kk < 8; ++kk) {
      half8_t bfc[8];
#pragma unroll
      for (int ct = 0; ct < 8; ++ct) bfc[ct] = bfn[ct];
      if (kk < 7) {
#pragma unroll
        for (int ct = 0; ct < 8; ++ct)
          bfn[ct] = *(const half8_t*)(Bn + ct * 4096 + (kk + 1) * 32);
      }
      const int cg = kk * 4 + q;
      half8_t af[2];
#pragma unroll
      for (int rt = 0; rt < 2; ++rt) {
        int r = wm + rt * 16 + l16;
        af[rt] = *(const half8_t*)(ldsA + (size_t)(r * 32 + (cg ^ (r & 7))) * 8);
      }
#pragma unroll
      for (int rt = 0; rt < 2; ++rt)
#pragma unroll
        for (int ct = 0; ct < 8; ++ct)
          acc[rt][ct] = __builtin_amdgcn_mfma_f32_16x16x32_f16(af[rt], bfc[ct], acc[rt][ct], 0, 0, 0);
    }
    // ---- n-tile epilogue: t1 store + row-stat accumulate ----
#pragma unroll
    for (int rt = 0; rt < 2; ++rt) {
#pragma unroll
      for (int rr = 0; rr < 4; ++rr) {
        int row = m0 + wm + rt * 16 + q * 4 + rr;  // C/D: col=lane&15, row=q*4+reg
        float vv[8];
        float s = 0.f, s2 = 0.f;
#pragma unroll
        for (int ct = 0; ct < 8; ++ct) {
          int col = n * 128 + ct * 16 + l16;
          float v = acc[rt][ct][rr] + bias[col];
          vv[ct] = v;
          s += v;
          s2 += v * v;
        }
        if (row < M) {
#pragma unroll
          for (int ct = 0; ct < 8; ++ct) {
            int col = n * 128 + ct * 16 + l16;
            outh[(size_t)row * 512 + col] = (_Float16)vv[ct];
          }
        }
        sA[rt][rr] += s;
        s2A[rt][rr] += s2;
      }
    }
  }

  // row (sum, sum^2): 16-lane reduce, direct store (wave owns its rows)
#pragma unroll
  for (int rt = 0; rt < 2; ++rt) {
#pragma unroll
    for (int rr = 0; rr < 4; ++rr) {
      float s = sA[rt][rr], s2 = s2A[rt][rr];
#pragma unroll
      for (int m = 1; m < 16; m <<= 1) {
        s += __shfl_xor(s, m, 64);
        s2 += __shfl_xor(s2, m, 64);
      }
      int row = m0 + wm + rt * 16 + q * 4 + rr;
      if (l16 == 0 && row < M) rstat[row] = make_float2(s, s2);
    }
  }
}

// ------------------------------- GEMM2 -------------------------------------
// h[M,256] (f16) += LN_relu(t1)[M,512] @ W2 + b2 (+ vn[batch[row]] if VN).
// 128x128 tile, depth-1 prefetch, LN+ReLU in writetile, rowfin fused in
// prologue. Epilogue via per-wave LDS (stride-68 pad). XCD-paired grid.
template <int VN>
__global__ __launch_bounds__(256, 2) void k_gemm2(
    const _Float16* __restrict__ A, const _Float16* __restrict__ BT,
    const float* __restrict__ bias, const float2* __restrict__ rstat,
    const float* __restrict__ lg, const float* __restrict__ lb,
    const float* __restrict__ vn, const int* __restrict__ batch,
    _Float16* __restrict__ outf, int M) {
  constexpr int K = 512, NN = 256, NT = K / 64;
  constexpr int EPS = 68;                      // epilogue row stride (f16)
  const int g = blockIdx.x;                    // 0..15
  const int mI = blockIdx.y * 8 + (g & 7);
  const int nI = g >> 3;
  const int mT = (M + 127) >> 7;
  if (mI >= mT) return;

  __shared__ _Float16 ldsbuf[4 * 64 * EPS];    // staging + padded epilogue
  _Float16* ldsA = ldsbuf;
  _Float16* ldsB = ldsbuf + 128 * 64;
  __shared__ float sg[512];
  __shared__ float sbt[512];
  const int tid = threadIdx.x;
  sg[tid] = lg[tid];
  sg[tid + 256] = lg[tid + 256];
  sbt[tid] = lb[tid];
  sbt[tid + 256] = lb[tid + 256];
  __syncthreads();

  const int lane = tid & 63;
  const int wv = tid >> 6;
  const int m0 = mI * 128;
  const int n0 = nI * 128;
  const int wm = (wv >> 1) * 64;
  const int wn = (wv & 1) * 64;
  const int q = lane >> 4;
  const int l16 = lane & 15;
  floatx4 acc[4][4] = {};

  size_t offA[4], offB[4];
  int ldsOff[4], gcolA[4];
  float aco[4], cco[4];
#pragma unroll
  for (int i = 0; i < 4; ++i) {
    int p = (i * 4 + wv) * 64 + lane;
    int r = p >> 3;
    int s = p & 7;
    int gg = s ^ (r & 7);
    int rowA = m0 + r;
    rowA = rowA < M ? rowA : (M - 1);
    offA[i] = (size_t)rowA * K + gg * 8;
    offB[i] = (size_t)(n0 + r) * K + gg * 8;
    ldsOff[i] = p * 8;
    gcolA[i] = gg * 8;
    float2 st = rstat[rowA];                 // raw (sum, sum^2)
    float mu = st.x * (1.f / 512.f);
    float var = st.y * (1.f / 512.f) - mu * mu;
    float rs = rsqrtf(var + 1e-5f);
    aco[i] = rs;
    cco[i] = -mu * rs;
  }
  half8_t ra[4], rb[4];
  auto loadtile = [&](int kt) {  // raw loads ONLY
#pragma unroll
    for (int i = 0; i < 4; ++i) {
      ra[i] = *(const half8_t*)(A + offA[i] + kt);
      rb[i] = *(const half8_t*)(BT + offB[i] + kt);
    }
  };
  auto writetile = [&](int kt) {  // LN+ReLU applied here (post-compute)
#pragma unroll
    for (int i = 0; i < 4; ++i) {
      int c0 = kt + gcolA[i];
      half8_t ya;
#pragma unroll
      for (int jj = 0; jj < 8; ++jj) {
        float e = fmaf((float)ra[i][jj], aco[i], cco[i]);
        float y = fmaf(e, sg[c0 + jj], sbt[c0 + jj]);
        ya[jj] = (_Float16)fmaxf(y, 0.f);
      }
      *(half8_t*)(ldsA + ldsOff[i]) = ya;
      *(half8_t*)(ldsB + ldsOff[i]) = rb[i];
    }
  };

  loadtile(0);
  writetile(0);
#pragma unroll
  for (int t = 0; t < NT; ++t) {
    __syncthreads();
    if (t + 1 < NT) loadtile((t + 1) * 64);
#pragma unroll
    for (int kk = 0; kk < 2; ++kk) {
      half8_t af[4], bf[4];
      const int c8 = kk * 4 + q;
#pragma unroll
      for (int rt = 0; rt < 4; ++rt) {
        int r = wm + rt * 16 + l16;
        af[rt] = *(const half8_t*)(ldsA + (size_t)(r * 8 + (c8 ^ (r & 7))) * 8);
      }
#pragma unroll
      for (int ct = 0; ct < 4; ++ct) {
        int n = wn + ct * 16 + l16;
        bf[ct] = *(const half8_t*)(ldsB + (size_t)(n * 8 + (c8 ^ (n & 7))) * 8);
      }
#pragma unroll
      for (int rt = 0; rt < 4; ++rt)
#pragma unroll
        for (int ct = 0; ct < 4; ++ct)
          acc[rt][ct] = __builtin_amdgcn_mfma_f32_16x16x32_f16(af[rt], bf[ct], acc[rt][ct], 0, 0, 0);
    }
    __syncthreads();
    if (t + 1 < NT) writetile((t + 1) * 64);
  }

  // ---- epilogue: per-wave LDS staging (stride-68 rows), coalesced RMW ----
  _Float16* epi = ldsbuf + wv * (64 * EPS);
#pragma unroll
  for (int rt = 0; rt < 4; ++rt) {
#pragma unroll
    for (int rr = 0; rr < 4; ++rr) {
      int rloc = rt * 16 + q * 4 + rr;
      int row = m0 + wm + rloc;
      int rowc = row < M ? row : (M - 1);
      int bb = 0;
      if constexpr (VN) bb = batch[rowc];
#pragma unroll
      for (int ct = 0; ct < 4; ++ct) {
        int cloc = ct * 16 + l16;
        int col = n0 + wn + cloc;
        float v = acc[rt][ct][rr] + bias[col];
        if constexpr (VN) v += vn[(size_t)bb * 256 + col];
        epi[rloc * EPS + cloc] = (_Float16)v;
      }
    }
  }
#pragma unroll
  for (int it = 0; it < 8; ++it) {
    int rloc = it * 8 + (lane >> 3);
    int row = m0 + wm + rloc;
    if (row < M) {
      int c0 = (lane & 7) * 8;
      size_t gidx = (size_t)row * NN + n0 + wn + c0;
      half8_t hv = *(const half8_t*)(outf + gidx);
      half8_t ev = *(const half8_t*)(epi + rloc * EPS + c0);
      half8_t o;
#pragma unroll
      for (int jj = 0; jj < 8; ++jj) o[jj] = (_Float16)((float)hv[jj] + (float)ev[jj]);
      *(half8_t*)(outf + gidx) = o;
    }
  }
}

// ------------- fused virtual-node update + next-layer LN -------------------
// block-per-batch (rows contiguous): vn[b] += mean(h rows) -> LDS; then
// hn[row] = relu(LN(h[row] + vn_new[b])) for all rows of the batch.
__global__ __launch_bounds__(256) void k_vnln(
    const _Float16* __restrict__ h, float* __restrict__ vn,
    const int* __restrict__ bptr, const float* __restrict__ g,
    const float* __restrict__ b, _Float16* __restrict__ hn) {
  __shared__ float red[3][256];
  __shared__ float svn[256];
  int bb = blockIdx.x;
  int w = threadIdx.x >> 6;
  int lane = threadIdx.x & 63;
  int n0 = bptr[bb], n1 = bptr[bb + 1];
  float a0 = 0.f, a1 = 0.f, a2 = 0.f, a3 = 0.f;
  for (int row = n0 + w; row < n1; row += 4) {
    half4_t xh = *(const half4_t*)(h + (size_t)row * 256 + lane * 4);
    a0 += (float)xh[0]; a1 += (float)xh[1];
    a2 += (float)xh[2]; a3 += (float)xh[3];
  }
  if (w > 0) {
    red[w - 1][lane * 4 + 0] = a0;
    red[w - 1][lane * 4 + 1] = a1;
    red[w - 1][lane * 4 + 2] = a2;
    red[w - 1][lane * 4 + 3] = a3;
  }
  __syncthreads();
  if (w == 0) {
    int c = n1 - n0;
    float ic = 1.f / (float)(c > 1 ? c : 1);
#pragma unroll
    for (int k = 0; k < 3; ++k) {
      a0 += red[k][lane * 4 + 0];
      a1 += red[k][lane * 4 + 1];
      a2 += red[k][lane * 4 + 2];
      a3 += red[k][lane * 4 + 3];
    }
    float4 vo = *(const float4*)(vn + (size_t)bb * 256 + lane * 4);
    vo.x += a0 * ic; vo.y += a1 * ic; vo.z += a2 * ic; vo.w += a3 * ic;
    *(float4*)(vn + (size_t)bb * 256 + lane * 4) = vo;
    svn[lane * 4 + 0] = vo.x;
    svn[lane * 4 + 1] = vo.y;
    svn[lane * 4 + 2] = vo.z;
    svn[lane * 4 + 3] = vo.w;
  }
  __syncthreads();
  float4 vv = *(const float4*)(svn + lane * 4);
  float4 gv = *(const float4*)(g + lane * 4);
  float4 bv = *(const float4*)(b + lane * 4);
  for (int row = n0 + w; row < n1; row += 4) {
    half4_t xh = *(const half4_t*)(h + (size_t)row * 256 + lane * 4);
    float x0 = (float)xh[0] + vv.x, x1 = (float)xh[1] + vv.y;
    float x2 = (float)xh[2] + vv.z, x3 = (float)xh[3] + vv.w;
    float s = wave_sum(x0 + x1 + x2 + x3);
    float mu = s * (1.f / 256.f);
    float d0 = x0 - mu, d1 = x1 - mu, d2 = x2 - mu, d3 = x3 - mu;
    float v = wave_sum(d0 * d0 + d1 * d1 + d2 * d2 + d3 * d3);
    float rstd = rsqrtf(v * (1.f / 256.f) + 1e-5f);
    half4_t o;
    o[0] = (_Float16)fmaxf(d0 * rstd * gv.x + bv.x, 0.f);
    o[1] = (_Float16)fmaxf(d1 * rstd * gv.y + bv.y, 0.f);
    o[2] = (_Float16)fmaxf(d2 * rstd * gv.z + bv.z, 0.f);
    o[3] = (_Float16)fmaxf(d3 * rstd * gv.w + bv.w, 0.f);
    *(half4_t*)(hn + (size_t)row * 256 + lane * 4) = o;
  }
}

// ---------- fused final vn update + LayerNorm + mean pool ------------------
// vn3 kept block-local (nothing reads it later); out[b] = mean(relu(LN(h+vn3)))
__global__ __launch_bounds__(256) void k_vnlnpool(
    const _Float16* __restrict__ h, const float* __restrict__ vn,
    const int* __restrict__ bptr, const float* __restrict__ g,
    const float* __restrict__ b, float* __restrict__ out) {
  __shared__ float red[3][256];
  __shared__ float svn[256];
  int bb = blockIdx.x;
  int w = threadIdx.x >> 6;
  int lane = threadIdx.x & 63;
  int n0 = bptr[bb], n1 = bptr[bb + 1];
  int c = n1 - n0;
  float ic = 1.f / (float)(c > 1 ? c : 1);
  float a0 = 0.f, a1 = 0.f, a2 = 0.f, a3 = 0.f;
  for (int row = n0 + w; row < n1; row += 4) {
    half4_t xh = *(const half4_t*)(h + (size_t)row * 256 + lane * 4);
    a0 += (float)xh[0]; a1 += (float)xh[1];
    a2 += (float)xh[2]; a3 += (float)xh[3];
  }
  if (w > 0) {
    red[w - 1][lane * 4 + 0] = a0;
    red[w - 1][lane * 4 + 1] = a1;
    red[w - 1][lane * 4 + 2] = a2;
    red[w - 1][lane * 4 + 3] = a3;
  }
  __syncthreads();
  if (w == 0) {
#pragma unroll
    for (int k = 0; k < 3; ++k) {
      a0 += red[k][lane * 4 + 0];
      a1 += red[k][lane * 4 + 1];
      a2 += red[k][lane * 4 + 2];
      a3 += red[k][lane * 4 + 3];
    }
    float4 vo = *(const float4*)(vn + (size_t)bb * 256 + lane * 4);
    svn[lane * 4 + 0] = vo.x + a0 * ic;
    svn[lane * 4 + 1] = vo.y + a1 * ic;
    svn[lane * 4 + 2] = vo.z + a2 * ic;
    svn[lane * 4 + 3] = vo.w + a3 * ic;
  }
  __syncthreads();
  float4 vv = *(const float4*)(svn + lane * 4);
  float4 gv = *(const float4*)(g + lane * 4);
  float4 bv = *(const float4*)(b + lane * 4);
  a0 = a1 = a2 = a3 = 0.f;
  for (int row = n0 + w; row < n1; row += 4) {
    half4_t xh = *(const half4_t*)(h + (size_t)row * 256 + lane * 4);
    float x0 = (float)xh[0] + vv.x, x1 = (float)xh[1] + vv.y;
    float x2 = (float)xh[2] + vv.z, x3 = (float)xh[3] + vv.w;
    float s = wave_sum(x0 + x1 + x2 + x3);
    float mu = s * (1.f / 256.f);
    float d0 = x0 - mu, d1 = x1 - mu, d2 = x2 - mu, d3 = x3 - mu;
    float v = wave_sum(d0 * d0 + d1 * d1 + d2 * d2 + d3 * d3);
    float rstd = rsqrtf(v * (1.f / 256.f) + 1e-5f);
    a0 += fmaxf(d0 * rstd * gv.x + bv.x, 0.f);
    a1 += fmaxf(d1 * rstd * gv.y + bv.y, 0.f);
    a2 += fmaxf(d2 * rstd * gv.z + bv.z, 0.f);
    a3 += fmaxf(d3 * rstd * gv.w + bv.w, 0.f);
  }
  __syncthreads();  // red reuse
  if (w > 0) {
    red[w - 1][lane * 4 + 0] = a0;
    red[w - 1][lane * 4 + 1] = a1;
    red[w - 1][lane * 4 + 2] = a2;
    red[w - 1][lane * 4 + 3] = a3;
  }
  __syncthreads();
  if (w == 0) {
#pragma unroll
    for (int k = 0; k < 3; ++k) {
      a0 += red[k][lane * 4 + 0];
      a1 += red[k][lane * 4 + 1];
      a2 += red[k][lane * 4 + 2];
      a3 += red[k][lane * 4 + 3];
    }
    float4 o = {a0 * ic, a1 * ic, a2 * ic, a3 * ic};
    *(float4*)(out + (size_t)bb * 256 + lane * 4) = o;
  }
}

// ---------------------------------------------------------------------------
extern "C" void kernel_launch(void* const* d_in, const int* in_sizes, int n_in,
                              void* d_out, int out_size, void* d_ws, size_t ws_size,
                              hipStream_t stream) {
  const float* x      = (const float*)d_in[0];
  const int*   ei     = (const int*)d_in[1];
  const float* eattr  = (const float*)d_in[2];
  const int*   batch  = (const int*)d_in[3];
  const float* nodeW  = (const float*)d_in[4];
  const float* nodeB  = (const float*)d_in[5];
  const float* edgeW  = (const float*)d_in[6];
  const float* edgeB  = (const float*)d_in[7];
  const float* vnemb  = (const float*)d_in[8];
  const float* lng    = (const float*)d_in[9];
  const float* lnb    = (const float*)d_in[10];
  const float* tparam = (const float*)d_in[11];
  const float* W1     = (const float*)d_in[12];
  const float* b1     = (const float*)d_in[13];
  const float* mlng   = (const float*)d_in[14];
  const float* mlnb   = (const float*)d_in[15];
  const float* W2     = (const float*)d_in[16];
  const float* b2     = (const float*)d_in[17];
  float* out = (float*)d_out;

  const int N = in_sizes[3];         // 100000
  const int E = in_sizes[1] / 2;     // 200000
  const int B = out_size / 256;      // 2048

  char* p = (char*)d_ws;
  auto take = [&](size_t bytes) -> char* {
    char* r = p;
    p += (bytes + 255) & ~(size_t)255;
    return r;
  };
  _Float16*  h   = (_Float16*)take((size_t)N * 256 * 2);  // f16 residual stream
  _Float16*  t1  = (_Float16*)take((size_t)N * 512 * 2);  // GEMM1 out [N,512]
  _Float16*  hn  = t1;                 // [N,256] f16 aliases t1 (disjoint lifetimes)
  _Float16*  agg = (_Float16*)take((size_t)N * 256 * 2);
  _Float16*  W1T = (_Float16*)take((size_t)3 * 512 * 256 * 2);
  _Float16*  W2T = (_Float16*)take((size_t)3 * 256 * 512 * 2);
  float2*    rstat = (float2*)take((size_t)N * 8);  // direct-stored per layer
  float*     vn  = (float*)take((size_t)B * 256 * 4);
  int*       bptr   = (int*)take((size_t)(B + 1) * 4);
  int*       deg    = (int*)take((size_t)N * 4);
  int*       indptr = (int*)take((size_t)(N + 1) * 4);
  int*       cursor = (int*)take((size_t)N * 4);
  int*       csr_src = (int*)take((size_t)E * 4);
  int*       csr_eid = (int*)take((size_t)E * 4);
  int*       bsum    = (int*)take(512 * 4);
  (void)ws_size; (void)n_in;

  hipMemsetAsync(deg, 0, (size_t)N * 4, stream);

  k_node_enc<<<(N + 7) / 8, 256, 0, stream>>>(x, nodeW, nodeB, h, N);
  k_bptr<<<(B + 256) / 256, 256, 0, stream>>>(batch, bptr, N, B);

  const int nbN = (N + 1023) / 1024;
  k_deg<<<(E + 255) / 256, 256, 0, stream>>>(ei, deg, E);
  k_scan1<<<nbN, 256, 0, stream>>>(deg, indptr + 1, bsum, N);
  k_scan2<<<1, 64, 0, stream>>>(bsum, nbN, indptr);
  k_scan3<<<nbN, 256, 0, stream>>>(indptr + 1, bsum, N);
  k_copy<<<(N + 255) / 256, 256, 0, stream>>>(indptr, cursor, N);
  k_csrfill<<<(E + 255) / 256, 256, 0, stream>>>(ei, cursor, csr_src, csr_eid, E);

  k_wcvt_all<<<3072, 256, 0, stream>>>(W1, W2, W1T, W2T);
  k_vninit<<<B, 256, 0, stream>>>(vnemb, vn);

  const int lnGrid = (N + 3) / 4;
  const int mTiles = (N + 127) / 128;
  const dim3 g2grid(16, (mTiles + 7) / 8);

  // layer 1 pre-LN (no pending vn)
  k_ln256<<<lnGrid, 256, 0, stream>>>(h, lng + 256, lnb + 256, hn, N);
  for (int l = 1; l <= 3; ++l) {
    k_aggregate<<<lnGrid, 256, 0, stream>>>(hn, eattr, edgeW, edgeB, indptr, csr_src, csr_eid,
                                            tparam + (l - 1), agg, N);
    k_gemm1<<<mTiles, 256, 0, stream>>>(
        agg, W1T + (size_t)(l - 1) * 512 * 256, b1 + (size_t)(l - 1) * 512, t1, rstat, N);
    if (l == 1)
      k_gemm2<0><<<g2grid, 256, 0, stream>>>(
          t1, W2T + (size_t)(l - 1) * 256 * 512, b2 + (size_t)(l - 1) * 256, rstat,
          mlng + (size_t)(l - 1) * 512, mlnb + (size_t)(l - 1) * 512, nullptr, nullptr, h, N);
    else
      k_gemm2<1><<<g2grid, 256, 0, stream>>>(
          t1, W2T + (size_t)(l - 1) * 256 * 512, b2 + (size_t)(l - 1) * 256, rstat,
          mlng + (size_t)(l - 1) * 512, mlnb + (size_t)(l - 1) * 512, vn, batch, h, N);
    if (l < 3)  // fused: vn update + layer-(l+1) LN
      k_vnln<<<B, 256, 0, stream>>>(h, vn, bptr,
                                    lng + (size_t)(l + 1) * 256, lnb + (size_t)(l + 1) * 256, hn);
    else        // fused: vn update + final LN + mean pool
      k_vnlnpool<<<B, 256, 0, stream>>>(h, vn, bptr, lng, lnb, out);
  }
}

// Round 13
// 767.654 us; speedup vs baseline: 1.2909x; 1.2909x over previous
//
#include <hip/hip_runtime.h>
#include <cstdint>
#include <cstddef>

// ---------------------------------------------------------------------------
// VirtualNodeGNN: 3x GENConv(softmax aggr) + virtual node + mean pool.
// R13 = R12's fusions + GEMM1 reverted to R11's LDS version.
//   R12 lesson: global->reg B-prefetch with head-of-loop register copy
//   serializes on vmcnt (L2 ~200cyc vs 77cyc MFMA; 120 VGPR -> Occ 15%)
//   -> GEMM1 64.6->140us. LDS staging decouples: MFMAs read the previous
//   barrier epoch while loads drain at the ds_write.
//   Kept from R12 (worth ~60us): k_vnln (vn update + next-layer LN fused,
//   block-per-batch) and k_vnlnpool (final vn + LN + pool).
// ---------------------------------------------------------------------------

typedef _Float16 half8_t __attribute__((ext_vector_type(8)));
typedef _Float16 half4_t __attribute__((ext_vector_type(4)));
typedef float    floatx4 __attribute__((ext_vector_type(4)));

#define DEVINL __device__ __forceinline__

DEVINL float wave_sum(float v) {
#pragma unroll
  for (int m = 32; m; m >>= 1) v += __shfl_xor(v, m, 64);
  return v;
}

// ------------------------------- node encoder ------------------------------
__global__ __launch_bounds__(256) void k_node_enc(
    const float* __restrict__ x, const float* __restrict__ W,
    const float* __restrict__ bias, _Float16* __restrict__ h, int Nr) {
  __shared__ float sW[9 * 256];
  __shared__ float sb[256];
  __shared__ float sx[72];
  const int j = threadIdx.x;
#pragma unroll
  for (int k = 0; k < 9; ++k) sW[k * 256 + j] = W[k * 256 + j];
  sb[j] = bias[j];
  const int row0 = blockIdx.x * 8;
  if (j < 72) {
    int p = row0 * 9 + j;
    sx[j] = (p < Nr * 9) ? x[p] : 0.f;
  }
  __syncthreads();
  for (int r = 0; r < 8; ++r) {
    int row = row0 + r;
    if (row >= Nr) break;
    float acc = sb[j];
#pragma unroll
    for (int k = 0; k < 9; ++k) acc = fmaf(sx[r * 9 + k], sW[k * 256 + j], acc);
    h[(size_t)row * 256 + j] = (_Float16)acc;
  }
}

// ---------------- batch ptr via binary search (batch sorted) ---------------
__global__ void k_bptr(const int* __restrict__ batch, int* __restrict__ bptr,
                       int N_, int B_) {
  int b = blockIdx.x * 256 + threadIdx.x;
  if (b > B_) return;
  int lo = 0, hi = N_;
  while (lo < hi) {
    int mid = (lo + hi) >> 1;
    if (batch[mid] < b) lo = mid + 1; else hi = mid;
  }
  bptr[b] = lo;
}

// ------------------------- CSR build (dst-sorted) --------------------------
__global__ void k_deg(const int* __restrict__ ei, int* __restrict__ deg, int E_) {
  int e = blockIdx.x * 256 + threadIdx.x;
  if (e < E_) atomicAdd(&deg[ei[E_ + e]], 1);  // row 1 of edge_index = dst
}

__global__ __launch_bounds__(256) void k_scan1(
    const int* __restrict__ in, int* __restrict__ out1, int* __restrict__ bsum, int n) {
  __shared__ int tmp[256];
  const int t = threadIdx.x;
  const int base = blockIdx.x * 1024;
  int v[4];
  int run = 0;
#pragma unroll
  for (int i = 0; i < 4; ++i) {
    int p = base + t * 4 + i;
    int xv = (p < n) ? in[p] : 0;
    run += xv;
    v[i] = run;
  }
  tmp[t] = run;
  __syncthreads();
  for (int off = 1; off < 256; off <<= 1) {
    int u = (t >= off) ? tmp[t - off] : 0;
    __syncthreads();
    tmp[t] += u;
    __syncthreads();
  }
  int excl = tmp[t] - run;
#pragma unroll
  for (int i = 0; i < 4; ++i) {
    int p = base + t * 4 + i;
    if (p < n) out1[p] = v[i] + excl;
  }
  if (t == 255) bsum[blockIdx.x] = tmp[255];
}

__global__ void k_scan2(int* bsum, int nb, int* ptr0) {
  if (threadIdx.x == 0 && blockIdx.x == 0) {
    int run = 0;
    for (int i = 0; i < nb; ++i) { int xv = bsum[i]; bsum[i] = run; run += xv; }
    ptr0[0] = 0;
  }
}

__global__ __launch_bounds__(256) void k_scan3(int* out1, const int* __restrict__ bsum, int n) {
  int add = bsum[blockIdx.x];
  int p0 = blockIdx.x * 1024 + threadIdx.x * 4;
#pragma unroll
  for (int i = 0; i < 4; ++i) {
    int p = p0 + i;
    if (p < n) out1[p] += add;
  }
}

__global__ void k_copy(const int* __restrict__ a, int* __restrict__ b, int n) {
  int i = blockIdx.x * 256 + threadIdx.x;
  if (i < n) b[i] = a[i];
}

__global__ void k_csrfill(const int* __restrict__ ei, int* __restrict__ cursor,
                          int* __restrict__ csr_src, int* __restrict__ csr_eid, int E_) {
  int e = blockIdx.x * 256 + threadIdx.x;
  if (e < E_) {
    int d = ei[E_ + e];
    int pos = atomicAdd(&cursor[d], 1);
    csr_src[pos] = ei[e];
    csr_eid[pos] = e;
  }
}

__global__ void k_vninit(const float* __restrict__ emb, float* __restrict__ vn) {
  vn[(size_t)blockIdx.x * 256 + threadIdx.x] = emb[threadIdx.x];
}

// ----------------- all-weights transpose+convert (one launch) --------------
__global__ __launch_bounds__(256) void k_wcvt_all(
    const float* __restrict__ W1, const float* __restrict__ W2,
    _Float16* __restrict__ W1T, _Float16* __restrict__ W2T) {
  int idx = blockIdx.x * 256 + threadIdx.x;
  int mat = idx >> 17;
  int rem = idx & 131071;
  if (mat < 3) {
    int k = rem >> 9, n = rem & 511;
    W1T[(size_t)mat * 131072 + (size_t)n * 256 + k] =
        (_Float16)W1[(size_t)mat * 131072 + rem];
  } else {
    int m = mat - 3;
    int k = rem >> 8, n = rem & 255;
    W2T[(size_t)m * 131072 + (size_t)n * 512 + k] =
        (_Float16)W2[(size_t)m * 131072 + rem];
  }
}

// ------------------------------ LayerNorm 256 ------------------------------
// used once (layer 1, no vn pending)
__global__ __launch_bounds__(256) void k_ln256(
    const _Float16* __restrict__ h, const float* __restrict__ g,
    const float* __restrict__ b, _Float16* __restrict__ out, int Nr) {
  int row = blockIdx.x * 4 + (threadIdx.x >> 6);
  if (row >= Nr) return;
  int lane = threadIdx.x & 63;
  half4_t xh = *(const half4_t*)(h + (size_t)row * 256 + lane * 4);
  float x0 = (float)xh[0], x1 = (float)xh[1], x2 = (float)xh[2], x3 = (float)xh[3];
  float s = wave_sum(x0 + x1 + x2 + x3);
  float mu = s * (1.f / 256.f);
  float d0 = x0 - mu, d1 = x1 - mu, d2 = x2 - mu, d3 = x3 - mu;
  float v = wave_sum(d0 * d0 + d1 * d1 + d2 * d2 + d3 * d3);
  float rstd = rsqrtf(v * (1.f / 256.f) + 1e-5f);
  float4 gv = *(const float4*)(g + lane * 4);
  float4 bv = *(const float4*)(b + lane * 4);
  half4_t o;
  o[0] = (_Float16)fmaxf(d0 * rstd * gv.x + bv.x, 0.f);
  o[1] = (_Float16)fmaxf(d1 * rstd * gv.y + bv.y, 0.f);
  o[2] = (_Float16)fmaxf(d2 * rstd * gv.z + bv.z, 0.f);
  o[3] = (_Float16)fmaxf(d3 * rstd * gv.w + bv.w, 0.f);
  *(half4_t*)(out + (size_t)row * 256 + lane * 4) = o;
}

// --------------------------- softmax aggregation ---------------------------
__global__ __launch_bounds__(256) void k_aggregate(
    const _Float16* __restrict__ hn, const float* __restrict__ eattr,
    const float* __restrict__ edgeW, const float* __restrict__ edgeB,
    const int* __restrict__ indptr, const int* __restrict__ csr_src,
    const int* __restrict__ csr_eid, const float* __restrict__ tptr,
    _Float16* __restrict__ agg, int Nr) {
  int node = blockIdx.x * 4 + (threadIdx.x >> 6);
  if (node >= Nr) return;
  int lane = threadIdx.x & 63;
  int j0 = lane * 4;
  float4 w0 = *(const float4*)(edgeW + j0);
  float4 w1 = *(const float4*)(edgeW + 256 + j0);
  float4 w2 = *(const float4*)(edgeW + 512 + j0);
  float4 wb = *(const float4*)(edgeB + j0);
  float W0[4] = {w0.x, w0.y, w0.z, w0.w};
  float W1r[4] = {w1.x, w1.y, w1.z, w1.w};
  float W2r[4] = {w2.x, w2.y, w2.z, w2.w};
  float WB[4] = {wb.x, wb.y, wb.z, wb.w};
  float tval = tptr[0];
  int e0 = indptr[node], e1 = indptr[node + 1];
  float D[4] = {0.f, 0.f, 0.f, 0.f};
  float Nu[4] = {0.f, 0.f, 0.f, 0.f};
  for (int s = e0; s < e1; ++s) {
    int srcn = csr_src[s];
    int eid = csr_eid[s];
    float ex0 = eattr[(size_t)eid * 3 + 0];
    float ex1 = eattr[(size_t)eid * 3 + 1];
    float ex2 = eattr[(size_t)eid * 3 + 2];
    half4_t hv = *(const half4_t*)(hn + (size_t)srcn * 256 + j0);
#pragma unroll
    for (int i = 0; i < 4; ++i) {
      float eaj = fmaf(ex0, W0[i], fmaf(ex1, W1r[i], fmaf(ex2, W2r[i], WB[i])));
      float msg = fmaxf((float)hv[i] + eaj, 0.f) + 1e-7f;
      float pr = __expf(msg * tval);
      D[i] += pr;
      Nu[i] = fmaf(pr, msg, Nu[i]);
    }
  }
  half4_t hs = *(const half4_t*)(hn + (size_t)node * 256 + j0);
  half4_t res;
#pragma unroll
  for (int i = 0; i < 4; ++i)
    res[i] = (_Float16)(Nu[i] / (D[i] + 1e-16f) + (float)hs[i]);
  *(half4_t*)(agg + (size_t)node * 256 + j0) = res;
}

// ------------------------------- GEMM1 -------------------------------------
// t1[M,512] = agg[M,256] @ W1 + b1 (f16 out) + rstat[row] = (sum, sum^2).
// Block = 64 rows x ALL 512 cols (LDS 48KB -> 3 blocks/CU). A staged ONCE
// (XOR-swizzled 16B chunks, 32/row); B (W1T, L2-resident) per (n,kt) with
// depth-1 register prefetch INTO LDS (ds_write absorbs the vmcnt drain).
// Wave owns 16 rows x 128 cols; row sums in regs, rstat direct store.
__global__ __launch_bounds__(256, 3) void k_gemm1(
    const _Float16* __restrict__ A, const _Float16* __restrict__ BT,
    const float* __restrict__ bias, _Float16* __restrict__ outh,
    float2* __restrict__ rstat, int M) {
  __shared__ _Float16 ldsA[64 * 256];    // 32 KB
  __shared__ _Float16 ldsB[128 * 64];    // 16 KB
  const int tid = threadIdx.x;
  const int lane = tid & 63;
  const int wv = tid >> 6;
  const int m0 = blockIdx.x * 64;
  const int wm = wv * 16;                // wave owns rows [wm, wm+16)
  const int q = lane >> 4;
  const int l16 = lane & 15;

  // ---- stage A once: 2048 16B chunks; slot s holds logical (r, c^(r&7)) ----
  {
    half8_t tmp[8];
    int ss[8];
#pragma unroll
    for (int g = 0; g < 8; ++g) {
      int s = g * 256 + tid;
      int r = s >> 5;
      int c = (s & 31) ^ (r & 7);
      int rowA = m0 + r;
      rowA = rowA < M ? rowA : (M - 1);
      tmp[g] = *(const half8_t*)(A + (size_t)rowA * 256 + c * 8);
      ss[g] = s;
    }
#pragma unroll
    for (int g = 0; g < 8; ++g)
      *(half8_t*)(ldsA + (size_t)ss[g] * 8) = tmp[g];
  }

  // ---- B staging (tile = 128 n-rows x 64 k of W1T[512,256]) ----
  size_t offB[4];
  int ldsOffB[4];
#pragma unroll
  for (int i = 0; i < 4; ++i) {
    int p = (i * 4 + wv) * 64 + lane;
    int r = p >> 3;
    int s = p & 7;
    int gg = s ^ (r & 7);
    offB[i] = (size_t)r * 256 + gg * 8;
    ldsOffB[i] = p * 8;
  }
  half8_t rb[4];
  auto loadB = [&](int j) {  // j = n*4 + t; raw loads only
    int n = j >> 2, t = j & 3;
    size_t base = (size_t)n * 128 * 256 + t * 64;
#pragma unroll
    for (int i = 0; i < 4; ++i)
      rb[i] = *(const half8_t*)(BT + base + offB[i]);
  };
  auto writeB = [&]() {
#pragma unroll
    for (int i = 0; i < 4; ++i)
      *(half8_t*)(ldsB + ldsOffB[i]) = rb[i];
  };

  floatx4 acc[8] = {};
  float sA[4] = {0.f, 0.f, 0.f, 0.f}, s2A[4] = {0.f, 0.f, 0.f, 0.f};

  loadB(0);
  writeB();
  for (int j = 0; j < 16; ++j) {
    __syncthreads();                     // B tile (and A on j=0) visible
    if (j + 1 < 16) loadB(j + 1);
    const int t = j & 3;
#pragma unroll
    for (int kk = 0; kk < 2; ++kk) {
      const int c8 = kk * 4 + q;         // k-chunk within tile (0..7)
      const int cg = t * 8 + c8;         // global k-chunk (0..31)
      int r = wm + l16;
      half8_t af = *(const half8_t*)(ldsA + (size_t)(r * 32 + (cg ^ (r & 7))) * 8);
      half8_t bf[8];
#pragma unroll
      for (int ct = 0; ct < 8; ++ct) {
        int n = ct * 16 + l16;
        bf[ct] = *(const half8_t*)(ldsB + (size_t)(n * 8 + (c8 ^ (n & 7))) * 8);
      }
#pragma unroll
      for (int ct = 0; ct < 8; ++ct)
        acc[ct] = __builtin_amdgcn_mfma_f32_16x16x32_f16(af, bf[ct], acc[ct], 0, 0, 0);
    }
    __syncthreads();
    if (j + 1 < 16) writeB();
    if ((j & 3) == 3) {                  // n-tile complete: epilogue
      int n = j >> 2;
#pragma unroll
      for (int rr = 0; rr < 4; ++rr) {
        int row = m0 + wm + q * 4 + rr;
        float vv[8];
        float s = 0.f, s2 = 0.f;
#pragma unroll
        for (int ct = 0; ct < 8; ++ct) {
          int col = n * 128 + ct * 16 + l16;
          float v = acc[ct][rr] + bias[col];
          vv[ct] = v;
          s += v;
          s2 += v * v;
        }
        if (row < M) {
#pragma unroll
          for (int ct = 0; ct < 8; ++ct) {
            int col = n * 128 + ct * 16 + l16;
            outh[(size_t)row * 512 + col] = (_Float16)vv[ct];
          }
        }
        sA[rr] += s;
        s2A[rr] += s2;
      }
#pragma unroll
      for (int ct = 0; ct < 8; ++ct)
        acc[ct] = floatx4{0.f, 0.f, 0.f, 0.f};
    }
  }

  // row (sum, sum^2): 16-lane reduce, direct store (wave owns its rows)
#pragma unroll
  for (int rr = 0; rr < 4; ++rr) {
    float s = sA[rr], s2 = s2A[rr];
#pragma unroll
    for (int m = 1; m < 16; m <<= 1) {
      s += __shfl_xor(s, m, 64);
      s2 += __shfl_xor(s2, m, 64);
    }
    int row = m0 + wm + q * 4 + rr;
    if (l16 == 0 && row < M) rstat[row] = make_float2(s, s2);
  }
}

// ------------------------------- GEMM2 -------------------------------------
// h[M,256] (f16) += LN_relu(t1)[M,512] @ W2 + b2 (+ vn[batch[row]] if VN).
// 128x128 tile, depth-1 prefetch, LN+ReLU in writetile, rowfin fused in
// prologue. Epilogue via per-wave LDS (stride-68 pad). XCD-paired grid.
template <int VN>
__global__ __launch_bounds__(256, 2) void k_gemm2(
    const _Float16* __restrict__ A, const _Float16* __restrict__ BT,
    const float* __restrict__ bias, const float2* __restrict__ rstat,
    const float* __restrict__ lg, const float* __restrict__ lb,
    const float* __restrict__ vn, const int* __restrict__ batch,
    _Float16* __restrict__ outf, int M) {
  constexpr int K = 512, NN = 256, NT = K / 64;
  constexpr int EPS = 68;                      // epilogue row stride (f16)
  const int g = blockIdx.x;                    // 0..15
  const int mI = blockIdx.y * 8 + (g & 7);
  const int nI = g >> 3;
  const int mT = (M + 127) >> 7;
  if (mI >= mT) return;

  __shared__ _Float16 ldsbuf[4 * 64 * EPS];    // staging + padded epilogue
  _Float16* ldsA = ldsbuf;
  _Float16* ldsB = ldsbuf + 128 * 64;
  __shared__ float sg[512];
  __shared__ float sbt[512];
  const int tid = threadIdx.x;
  sg[tid] = lg[tid];
  sg[tid + 256] = lg[tid + 256];
  sbt[tid] = lb[tid];
  sbt[tid + 256] = lb[tid + 256];
  __syncthreads();

  const int lane = tid & 63;
  const int wv = tid >> 6;
  const int m0 = mI * 128;
  const int n0 = nI * 128;
  const int wm = (wv >> 1) * 64;
  const int wn = (wv & 1) * 64;
  const int q = lane >> 4;
  const int l16 = lane & 15;
  floatx4 acc[4][4] = {};

  size_t offA[4], offB[4];
  int ldsOff[4], gcolA[4];
  float aco[4], cco[4];
#pragma unroll
  for (int i = 0; i < 4; ++i) {
    int p = (i * 4 + wv) * 64 + lane;
    int r = p >> 3;
    int s = p & 7;
    int gg = s ^ (r & 7);
    int rowA = m0 + r;
    rowA = rowA < M ? rowA : (M - 1);
    offA[i] = (size_t)rowA * K + gg * 8;
    offB[i] = (size_t)(n0 + r) * K + gg * 8;
    ldsOff[i] = p * 8;
    gcolA[i] = gg * 8;
    float2 st = rstat[rowA];                 // raw (sum, sum^2)
    float mu = st.x * (1.f / 512.f);
    float var = st.y * (1.f / 512.f) - mu * mu;
    float rs = rsqrtf(var + 1e-5f);
    aco[i] = rs;
    cco[i] = -mu * rs;
  }
  half8_t ra[4], rb[4];
  auto loadtile = [&](int kt) {  // raw loads ONLY
#pragma unroll
    for (int i = 0; i < 4; ++i) {
      ra[i] = *(const half8_t*)(A + offA[i] + kt);
      rb[i] = *(const half8_t*)(BT + offB[i] + kt);
    }
  };
  auto writetile = [&](int kt) {  // LN+ReLU applied here (post-compute)
#pragma unroll
    for (int i = 0; i < 4; ++i) {
      int c0 = kt + gcolA[i];
      half8_t ya;
#pragma unroll
      for (int jj = 0; jj < 8; ++jj) {
        float e = fmaf((float)ra[i][jj], aco[i], cco[i]);
        float y = fmaf(e, sg[c0 + jj], sbt[c0 + jj]);
        ya[jj] = (_Float16)fmaxf(y, 0.f);
      }
      *(half8_t*)(ldsA + ldsOff[i]) = ya;
      *(half8_t*)(ldsB + ldsOff[i]) = rb[i];
    }
  };

  loadtile(0);
  writetile(0);
#pragma unroll
  for (int t = 0; t < NT; ++t) {
    __syncthreads();
    if (t + 1 < NT) loadtile((t + 1) * 64);
#pragma unroll
    for (int kk = 0; kk < 2; ++kk) {
      half8_t af[4], bf[4];
      const int c8 = kk * 4 + q;
#pragma unroll
      for (int rt = 0; rt < 4; ++rt) {
        int r = wm + rt * 16 + l16;
        af[rt] = *(const half8_t*)(ldsA + (size_t)(r * 8 + (c8 ^ (r & 7))) * 8);
      }
#pragma unroll
      for (int ct = 0; ct < 4; ++ct) {
        int n = wn + ct * 16 + l16;
        bf[ct] = *(const half8_t*)(ldsB + (size_t)(n * 8 + (c8 ^ (n & 7))) * 8);
      }
#pragma unroll
      for (int rt = 0; rt < 4; ++rt)
#pragma unroll
        for (int ct = 0; ct < 4; ++ct)
          acc[rt][ct] = __builtin_amdgcn_mfma_f32_16x16x32_f16(af[rt], bf[ct], acc[rt][ct], 0, 0, 0);
    }
    __syncthreads();
    if (t + 1 < NT) writetile((t + 1) * 64);
  }

  // ---- epilogue: per-wave LDS staging (stride-68 rows), coalesced RMW ----
  _Float16* epi = ldsbuf + wv * (64 * EPS);
#pragma unroll
  for (int rt = 0; rt < 4; ++rt) {
#pragma unroll
    for (int rr = 0; rr < 4; ++rr) {
      int rloc = rt * 16 + q * 4 + rr;
      int row = m0 + wm + rloc;
      int rowc = row < M ? row : (M - 1);
      int bb = 0;
      if constexpr (VN) bb = batch[rowc];
#pragma unroll
      for (int ct = 0; ct < 4; ++ct) {
        int cloc = ct * 16 + l16;
        int col = n0 + wn + cloc;
        float v = acc[rt][ct][rr] + bias[col];
        if constexpr (VN) v += vn[(size_t)bb * 256 + col];
        epi[rloc * EPS + cloc] = (_Float16)v;
      }
    }
  }
#pragma unroll
  for (int it = 0; it < 8; ++it) {
    int rloc = it * 8 + (lane >> 3);
    int row = m0 + wm + rloc;
    if (row < M) {
      int c0 = (lane & 7) * 8;
      size_t gidx = (size_t)row * NN + n0 + wn + c0;
      half8_t hv = *(const half8_t*)(outf + gidx);
      half8_t ev = *(const half8_t*)(epi + rloc * EPS + c0);
      half8_t o;
#pragma unroll
      for (int jj = 0; jj < 8; ++jj) o[jj] = (_Float16)((float)hv[jj] + (float)ev[jj]);
      *(half8_t*)(outf + gidx) = o;
    }
  }
}

// ------------- fused virtual-node update + next-layer LN -------------------
__global__ __launch_bounds__(256) void k_vnln(
    const _Float16* __restrict__ h, float* __restrict__ vn,
    const int* __restrict__ bptr, const float* __restrict__ g,
    const float* __restrict__ b, _Float16* __restrict__ hn) {
  __shared__ float red[3][256];
  __shared__ float svn[256];
  int bb = blockIdx.x;
  int w = threadIdx.x >> 6;
  int lane = threadIdx.x & 63;
  int n0 = bptr[bb], n1 = bptr[bb + 1];
  float a0 = 0.f, a1 = 0.f, a2 = 0.f, a3 = 0.f;
  for (int row = n0 + w; row < n1; row += 4) {
    half4_t xh = *(const half4_t*)(h + (size_t)row * 256 + lane * 4);
    a0 += (float)xh[0]; a1 += (float)xh[1];
    a2 += (float)xh[2]; a3 += (float)xh[3];
  }
  if (w > 0) {
    red[w - 1][lane * 4 + 0] = a0;
    red[w - 1][lane * 4 + 1] = a1;
    red[w - 1][lane * 4 + 2] = a2;
    red[w - 1][lane * 4 + 3] = a3;
  }
  __syncthreads();
  if (w == 0) {
    int c = n1 - n0;
    float ic = 1.f / (float)(c > 1 ? c : 1);
#pragma unroll
    for (int k = 0; k < 3; ++k) {
      a0 += red[k][lane * 4 + 0];
      a1 += red[k][lane * 4 + 1];
      a2 += red[k][lane * 4 + 2];
      a3 += red[k][lane * 4 + 3];
    }
    float4 vo = *(const float4*)(vn + (size_t)bb * 256 + lane * 4);
    vo.x += a0 * ic; vo.y += a1 * ic; vo.z += a2 * ic; vo.w += a3 * ic;
    *(float4*)(vn + (size_t)bb * 256 + lane * 4) = vo;
    svn[lane * 4 + 0] = vo.x;
    svn[lane * 4 + 1] = vo.y;
    svn[lane * 4 + 2] = vo.z;
    svn[lane * 4 + 3] = vo.w;
  }
  __syncthreads();
  float4 vv = *(const float4*)(svn + lane * 4);
  float4 gv = *(const float4*)(g + lane * 4);
  float4 bv = *(const float4*)(b + lane * 4);
  for (int row = n0 + w; row < n1; row += 4) {
    half4_t xh = *(const half4_t*)(h + (size_t)row * 256 + lane * 4);
    float x0 = (float)xh[0] + vv.x, x1 = (float)xh[1] + vv.y;
    float x2 = (float)xh[2] + vv.z, x3 = (float)xh[3] + vv.w;
    float s = wave_sum(x0 + x1 + x2 + x3);
    float mu = s * (1.f / 256.f);
    float d0 = x0 - mu, d1 = x1 - mu, d2 = x2 - mu, d3 = x3 - mu;
    float v = wave_sum(d0 * d0 + d1 * d1 + d2 * d2 + d3 * d3);
    float rstd = rsqrtf(v * (1.f / 256.f) + 1e-5f);
    half4_t o;
    o[0] = (_Float16)fmaxf(d0 * rstd * gv.x + bv.x, 0.f);
    o[1] = (_Float16)fmaxf(d1 * rstd * gv.y + bv.y, 0.f);
    o[2] = (_Float16)fmaxf(d2 * rstd * gv.z + bv.z, 0.f);
    o[3] = (_Float16)fmaxf(d3 * rstd * gv.w + bv.w, 0.f);
    *(half4_t*)(hn + (size_t)row * 256 + lane * 4) = o;
  }
}

// ---------- fused final vn update + LayerNorm + mean pool ------------------
__global__ __launch_bounds__(256) void k_vnlnpool(
    const _Float16* __restrict__ h, const float* __restrict__ vn,
    const int* __restrict__ bptr, const float* __restrict__ g,
    const float* __restrict__ b, float* __restrict__ out) {
  __shared__ float red[3][256];
  __shared__ float svn[256];
  int bb = blockIdx.x;
  int w = threadIdx.x >> 6;
  int lane = threadIdx.x & 63;
  int n0 = bptr[bb], n1 = bptr[bb + 1];
  int c = n1 - n0;
  float ic = 1.f / (float)(c > 1 ? c : 1);
  float a0 = 0.f, a1 = 0.f, a2 = 0.f, a3 = 0.f;
  for (int row = n0 + w; row < n1; row += 4) {
    half4_t xh = *(const half4_t*)(h + (size_t)row * 256 + lane * 4);
    a0 += (float)xh[0]; a1 += (float)xh[1];
    a2 += (float)xh[2]; a3 += (float)xh[3];
  }
  if (w > 0) {
    red[w - 1][lane * 4 + 0] = a0;
    red[w - 1][lane * 4 + 1] = a1;
    red[w - 1][lane * 4 + 2] = a2;
    red[w - 1][lane * 4 + 3] = a3;
  }
  __syncthreads();
  if (w == 0) {
#pragma unroll
    for (int k = 0; k < 3; ++k) {
      a0 += red[k][lane * 4 + 0];
      a1 += red[k][lane * 4 + 1];
      a2 += red[k][lane * 4 + 2];
      a3 += red[k][lane * 4 + 3];
    }
    float4 vo = *(const float4*)(vn + (size_t)bb * 256 + lane * 4);
    svn[lane * 4 + 0] = vo.x + a0 * ic;
    svn[lane * 4 + 1] = vo.y + a1 * ic;
    svn[lane * 4 + 2] = vo.z + a2 * ic;
    svn[lane * 4 + 3] = vo.w + a3 * ic;
  }
  __syncthreads();
  float4 vv = *(const float4*)(svn + lane * 4);
  float4 gv = *(const float4*)(g + lane * 4);
  float4 bv = *(const float4*)(b + lane * 4);
  a0 = a1 = a2 = a3 = 0.f;
  for (int row = n0 + w; row < n1; row += 4) {
    half4_t xh = *(const half4_t*)(h + (size_t)row * 256 + lane * 4);
    float x0 = (float)xh[0] + vv.x, x1 = (float)xh[1] + vv.y;
    float x2 = (float)xh[2] + vv.z, x3 = (float)xh[3] + vv.w;
    float s = wave_sum(x0 + x1 + x2 + x3);
    float mu = s * (1.f / 256.f);
    float d0 = x0 - mu, d1 = x1 - mu, d2 = x2 - mu, d3 = x3 - mu;
    float v = wave_sum(d0 * d0 + d1 * d1 + d2 * d2 + d3 * d3);
    float rstd = rsqrtf(v * (1.f / 256.f) + 1e-5f);
    a0 += fmaxf(d0 * rstd * gv.x + bv.x, 0.f);
    a1 += fmaxf(d1 * rstd * gv.y + bv.y, 0.f);
    a2 += fmaxf(d2 * rstd * gv.z + bv.z, 0.f);
    a3 += fmaxf(d3 * rstd * gv.w + bv.w, 0.f);
  }
  __syncthreads();  // red reuse
  if (w > 0) {
    red[w - 1][lane * 4 + 0] = a0;
    red[w - 1][lane * 4 + 1] = a1;
    red[w - 1][lane * 4 + 2] = a2;
    red[w - 1][lane * 4 + 3] = a3;
  }
  __syncthreads();
  if (w == 0) {
#pragma unroll
    for (int k = 0; k < 3; ++k) {
      a0 += red[k][lane * 4 + 0];
      a1 += red[k][lane * 4 + 1];
      a2 += red[k][lane * 4 + 2];
      a3 += red[k][lane * 4 + 3];
    }
    float4 o = {a0 * ic, a1 * ic, a2 * ic, a3 * ic};
    *(float4*)(out + (size_t)bb * 256 + lane * 4) = o;
  }
}

// ---------------------------------------------------------------------------
extern "C" void kernel_launch(void* const* d_in, const int* in_sizes, int n_in,
                              void* d_out, int out_size, void* d_ws, size_t ws_size,
                              hipStream_t stream) {
  const float* x      = (const float*)d_in[0];
  const int*   ei     = (const int*)d_in[1];
  const float* eattr  = (const float*)d_in[2];
  const int*   batch  = (const int*)d_in[3];
  const float* nodeW  = (const float*)d_in[4];
  const float* nodeB  = (const float*)d_in[5];
  const float* edgeW  = (const float*)d_in[6];
  const float* edgeB  = (const float*)d_in[7];
  const float* vnemb  = (const float*)d_in[8];
  const float* lng    = (const float*)d_in[9];
  const float* lnb    = (const float*)d_in[10];
  const float* tparam = (const float*)d_in[11];
  const float* W1     = (const float*)d_in[12];
  const float* b1     = (const float*)d_in[13];
  const float* mlng   = (const float*)d_in[14];
  const float* mlnb   = (const float*)d_in[15];
  const float* W2     = (const float*)d_in[16];
  const float* b2     = (const float*)d_in[17];
  float* out = (float*)d_out;

  const int N = in_sizes[3];         // 100000
  const int E = in_sizes[1] / 2;     // 200000
  const int B = out_size / 256;      // 2048

  char* p = (char*)d_ws;
  auto take = [&](size_t bytes) -> char* {
    char* r = p;
    p += (bytes + 255) & ~(size_t)255;
    return r;
  };
  _Float16*  h   = (_Float16*)take((size_t)N * 256 * 2);  // f16 residual stream
  _Float16*  t1  = (_Float16*)take((size_t)N * 512 * 2);  // GEMM1 out [N,512]
  _Float16*  hn  = t1;                 // [N,256] f16 aliases t1 (disjoint lifetimes)
  _Float16*  agg = (_Float16*)take((size_t)N * 256 * 2);
  _Float16*  W1T = (_Float16*)take((size_t)3 * 512 * 256 * 2);
  _Float16*  W2T = (_Float16*)take((size_t)3 * 256 * 512 * 2);
  float2*    rstat = (float2*)take((size_t)N * 8);  // direct-stored per layer
  float*     vn  = (float*)take((size_t)B * 256 * 4);
  int*       bptr   = (int*)take((size_t)(B + 1) * 4);
  int*       deg    = (int*)take((size_t)N * 4);
  int*       indptr = (int*)take((size_t)(N + 1) * 4);
  int*       cursor = (int*)take((size_t)N * 4);
  int*       csr_src = (int*)take((size_t)E * 4);
  int*       csr_eid = (int*)take((size_t)E * 4);
  int*       bsum    = (int*)take(512 * 4);
  (void)ws_size; (void)n_in;

  hipMemsetAsync(deg, 0, (size_t)N * 4, stream);

  k_node_enc<<<(N + 7) / 8, 256, 0, stream>>>(x, nodeW, nodeB, h, N);
  k_bptr<<<(B + 256) / 256, 256, 0, stream>>>(batch, bptr, N, B);

  const int nbN = (N + 1023) / 1024;
  k_deg<<<(E + 255) / 256, 256, 0, stream>>>(ei, deg, E);
  k_scan1<<<nbN, 256, 0, stream>>>(deg, indptr + 1, bsum, N);
  k_scan2<<<1, 64, 0, stream>>>(bsum, nbN, indptr);
  k_scan3<<<nbN, 256, 0, stream>>>(indptr + 1, bsum, N);
  k_copy<<<(N + 255) / 256, 256, 0, stream>>>(indptr, cursor, N);
  k_csrfill<<<(E + 255) / 256, 256, 0, stream>>>(ei, cursor, csr_src, csr_eid, E);

  k_wcvt_all<<<3072, 256, 0, stream>>>(W1, W2, W1T, W2T);
  k_vninit<<<B, 256, 0, stream>>>(vnemb, vn);

  const int lnGrid = (N + 3) / 4;
  const int mTiles1 = (N + 63) / 64;
  const int mTiles2 = (N + 127) / 128;
  const dim3 g2grid(16, (mTiles2 + 7) / 8);

  // layer 1 pre-LN (no pending vn)
  k_ln256<<<lnGrid, 256, 0, stream>>>(h, lng + 256, lnb + 256, hn, N);
  for (int l = 1; l <= 3; ++l) {
    k_aggregate<<<lnGrid, 256, 0, stream>>>(hn, eattr, edgeW, edgeB, indptr, csr_src, csr_eid,
                                            tparam + (l - 1), agg, N);
    k_gemm1<<<mTiles1, 256, 0, stream>>>(
        agg, W1T + (size_t)(l - 1) * 512 * 256, b1 + (size_t)(l - 1) * 512, t1, rstat, N);
    if (l == 1)
      k_gemm2<0><<<g2grid, 256, 0, stream>>>(
          t1, W2T + (size_t)(l - 1) * 256 * 512, b2 + (size_t)(l - 1) * 256, rstat,
          mlng + (size_t)(l - 1) * 512, mlnb + (size_t)(l - 1) * 512, nullptr, nullptr, h, N);
    else
      k_gemm2<1><<<g2grid, 256, 0, stream>>>(
          t1, W2T + (size_t)(l - 1) * 256 * 512, b2 + (size_t)(l - 1) * 256, rstat,
          mlng + (size_t)(l - 1) * 512, mlnb + (size_t)(l - 1) * 512, vn, batch, h, N);
    if (l < 3)  // fused: vn update + layer-(l+1) LN
      k_vnln<<<B, 256, 0, stream>>>(h, vn, bptr,
                                    lng + (size_t)(l + 1) * 256, lnb + (size_t)(l + 1) * 256, hn);
    else        // fused: vn update + final LN + mean pool
      k_vnlnpool<<<B, 256, 0, stream>>>(h, vn, bptr, lng, lnb, out);
  }
}